// Round 1
// baseline (891.123 us; speedup 1.0000x reference)
//
#include <hip/hip_runtime.h>

typedef short sv8 __attribute__((ext_vector_type(8)));
typedef float fv4 __attribute__((ext_vector_type(4)));

#define MFMA16(a, b, c) __builtin_amdgcn_mfma_f32_16x16x32_bf16((a), (b), (c), 0, 0, 0)

__device__ __forceinline__ unsigned short f2bf(float f) {
    unsigned u = __builtin_bit_cast(unsigned, f);
    unsigned r = (u + 0x7FFF + ((u >> 16) & 1)) >> 16;
    return (unsigned short)r;
}

// ---------------- dims ----------------
// latent (2,1024,1024)  x (2,4096,2048)
// Wq(1024,1024) bq  Wc(2048,256) bc  Wk(256,1024) bk  Wv(256,1024) bv  Wo(1024,1024) bo
constexpr int BB = 2, LL = 1024, SS = 4096, LD = 1024, HH = 16, DD = 64;

// ============================================================================
// Fused weight transpose: W (K x N, f32) -> Wt (N x K, bf16), all 5 weights.
// ============================================================================
__global__ __launch_bounds__(256) void transpose_weights(
    const float* __restrict__ Wc, const float* __restrict__ Wk, const float* __restrict__ Wv,
    const float* __restrict__ Wq, const float* __restrict__ Wo,
    unsigned short* __restrict__ Tc, unsigned short* __restrict__ Tk,
    unsigned short* __restrict__ Tv, unsigned short* __restrict__ Tq,
    unsigned short* __restrict__ To)
{
    __shared__ __align__(16) unsigned short tile[64][68];
    int bid = blockIdx.x;
    const float* W; unsigned short* T; int K, N, tix;
    if (bid < 128)      { W = Wc; T = Tc; K = 2048; N = 256;  tix = bid; }
    else if (bid < 192) { W = Wk; T = Tk; K = 256;  N = 1024; tix = bid - 128; }
    else if (bid < 256) { W = Wv; T = Tv; K = 256;  N = 1024; tix = bid - 192; }
    else if (bid < 512) { W = Wq; T = Tq; K = 1024; N = 1024; tix = bid - 256; }
    else                { W = Wo; T = To; K = 1024; N = 1024; tix = bid - 512; }
    int tn = N >> 6;
    int k0 = (tix / tn) << 6, n0 = (tix % tn) << 6;
    int t = threadIdx.x;
    int r = t >> 4, c4 = (t & 15) * 4;
#pragma unroll
    for (int i = 0; i < 4; i++) {
        int k = r + i * 16;
        float4 f = *(const float4*)(W + (size_t)(k0 + k) * N + n0 + c4);
        tile[k][c4 + 0] = f2bf(f.x); tile[k][c4 + 1] = f2bf(f.y);
        tile[k][c4 + 2] = f2bf(f.z); tile[k][c4 + 3] = f2bf(f.w);
    }
    __syncthreads();
#pragma unroll
    for (int i = 0; i < 4; i++) {
        int n = r + i * 16;
        ushort4 o;
        o.x = tile[c4 + 0][n]; o.y = tile[c4 + 1][n];
        o.z = tile[c4 + 2][n]; o.w = tile[c4 + 3][n];
        *(ushort4*)(T + (size_t)(n0 + n) * K + k0 + c4) = o;
    }
}

// ============================================================================
// V (b, s, h*64+d) bf16 -> Vt (b, h, d, s) bf16
// ============================================================================
__global__ __launch_bounds__(256) void transpose_v(
    const unsigned short* __restrict__ V, unsigned short* __restrict__ Vt)
{
    __shared__ __align__(16) unsigned short tile[64][68];
    int s0 = blockIdx.x * 64;
    int h = blockIdx.y, b = blockIdx.z;
    int t = threadIdx.x;
    int r = t >> 4, c4 = (t & 15) * 4;
#pragma unroll
    for (int i = 0; i < 4; i++) {
        int s = r + i * 16;
        ushort4 v = *(const ushort4*)(V + (size_t)(b * SS + s0 + s) * LD + h * DD + c4);
        tile[s][c4 + 0] = v.x; tile[s][c4 + 1] = v.y;
        tile[s][c4 + 2] = v.z; tile[s][c4 + 3] = v.w;
    }
    __syncthreads();
#pragma unroll
    for (int i = 0; i < 4; i++) {
        int d = r + i * 16;
        ushort4 o;
        o.x = tile[c4 + 0][d]; o.y = tile[c4 + 1][d];
        o.z = tile[c4 + 2][d]; o.w = tile[c4 + 3][d];
        *(ushort4*)(Vt + ((size_t)(b * HH + h) * DD + d) * SS + s0 + c4) = o;
    }
}

// ============================================================================
// Templated GEMM: C(MxN) = (A(MxK) @ B) * scale + bias*scale
// A: f32 or bf16 row-major; Bt: N x K bf16 (pre-transposed); C: f32 or bf16.
// 4 waves in 2x2; BK=32; 16x16x32 bf16 MFMA.
// ============================================================================
template<int BM, int BN, bool A_F32, bool C_F32>
__global__ __launch_bounds__(256) void gemm_bias(
    const void* __restrict__ Ag, const unsigned short* __restrict__ Bt,
    const float* __restrict__ bias, void* __restrict__ Cg,
    int M, int N, int K, float scale)
{
    constexpr int LDT = 40;  // 80 B row stride: 16B-aligned, bank-spread
    __shared__ __align__(16) unsigned short As[BM * LDT];
    __shared__ __align__(16) unsigned short Bs[BN * LDT];
    __shared__ float bias_s[BN];
    const int t = threadIdx.x;
    const int m0 = blockIdx.x * BM, n0 = blockIdx.y * BN;
    for (int i = t; i < BN; i += 256) bias_s[i] = bias[n0 + i];
    const int w = t >> 6, lane = t & 63, l15 = lane & 15, quad = lane >> 4;
    constexpr int WM = BM / 2, WN = BN / 2;
    constexpr int MT = WM / 16, NT = WN / 16;
    const int wm = (w >> 1) * WM, wn = (w & 1) * WN;
    fv4 acc[MT][NT] = {};
    const int r8 = t >> 3, c4 = (t & 7) * 4;
    for (int k0 = 0; k0 < K; k0 += 32) {
#pragma unroll
        for (int i = 0; i < BM / 32; i++) {
            int row = r8 + i * 32;
            ushort4 v;
            if constexpr (A_F32) {
                float4 f = *(const float4*)((const float*)Ag + (size_t)(m0 + row) * K + k0 + c4);
                v.x = f2bf(f.x); v.y = f2bf(f.y); v.z = f2bf(f.z); v.w = f2bf(f.w);
            } else {
                v = *(const ushort4*)((const unsigned short*)Ag + (size_t)(m0 + row) * K + k0 + c4);
            }
            *(ushort4*)&As[row * LDT + c4] = v;
        }
#pragma unroll
        for (int i = 0; i < BN / 32; i++) {
            int row = r8 + i * 32;
            ushort4 v = *(const ushort4*)(Bt + (size_t)(n0 + row) * K + k0 + c4);
            *(ushort4*)&Bs[row * LDT + c4] = v;
        }
        __syncthreads();
        sv8 af[MT], bfr[NT];
#pragma unroll
        for (int mt = 0; mt < MT; mt++)
            af[mt] = *(const sv8*)&As[(wm + mt * 16 + l15) * LDT + quad * 8];
#pragma unroll
        for (int nt = 0; nt < NT; nt++)
            bfr[nt] = *(const sv8*)&Bs[(wn + nt * 16 + l15) * LDT + quad * 8];
#pragma unroll
        for (int mt = 0; mt < MT; mt++)
#pragma unroll
            for (int nt = 0; nt < NT; nt++)
                acc[mt][nt] = MFMA16(af[mt], bfr[nt], acc[mt][nt]);
        __syncthreads();
    }
    // epilogue: C row = quad*4+reg, col = lane&15 (m89-verified layout)
#pragma unroll
    for (int mt = 0; mt < MT; mt++) {
#pragma unroll
        for (int nt = 0; nt < NT; nt++) {
            int col = n0 + wn + nt * 16 + l15;
            float bb = bias_s[wn + nt * 16 + l15];
#pragma unroll
            for (int r = 0; r < 4; r++) {
                int row = m0 + wm + mt * 16 + quad * 4 + r;
                float vv = (acc[mt][nt][r] + bb) * scale;
                if constexpr (C_F32) ((float*)Cg)[(size_t)row * N + col] = vv;
                else ((unsigned short*)Cg)[(size_t)row * N + col] = f2bf(vv);
            }
        }
    }
}

// ============================================================================
// Attention: per WG one (b, h, 64-row L tile). Two passes over S chunks of 128.
// Pass 1: row sums of exp(scores) (no max subtraction; |scores| ~ 1).
// Pass 2: recompute scores, write normalized weights to d_out, PV-accumulate O.
// This round: T14 async-STAGE split (issue next chunk's global loads into regs
// right after the consuming barrier; ds_write them next iteration) + T5
// s_setprio around MFMA clusters.
// ============================================================================
constexpr int SC  = 128;
constexpr int KLD = 72;   // 144 B rows (16B mult)
constexpr int VLD = 136;  // 272 B rows (16B mult)

__global__ __launch_bounds__(256) void attn_kernel(
    const unsigned short* __restrict__ Qw,   // (B,L,1024) bf16, pre-scaled 1/8
    const unsigned short* __restrict__ Kw,   // (B,S,1024) bf16
    const unsigned short* __restrict__ Vtw,  // (B,H,D,S) bf16
    float* __restrict__ Wout,                // (B,H,L,S) f32
    unsigned short* __restrict__ Ow)         // (B,L,1024) bf16
{
    __shared__ __align__(16) unsigned short Ks[SC * KLD];
    __shared__ __align__(16) unsigned short Vs[DD * VLD];
    __shared__ __align__(16) unsigned short Ps[4 * 16 * VLD];
    const int bid = blockIdx.x;
    const int lt = bid & 15, h = (bid >> 4) & 15, b = bid >> 8;
    const int l0 = lt * 64;
    const int t = threadIdx.x, w = t >> 6, lane = t & 63, l15 = lane & 15, quad = lane >> 4;

    // Q fragments direct from global (each element used by exactly one lane)
    const unsigned short* qrow = Qw + (size_t)(b * LL + l0 + w * 16 + l15) * LD + h * DD;
    const sv8 aq0 = *(const sv8*)(qrow + quad * 8);
    const sv8 aq1 = *(const sv8*)(qrow + 32 + quad * 8);

    const unsigned short* kg0 = Kw + (size_t)(b * SS) * LD + h * DD;
    const int kr = t >> 3, kc = (t & 7) * 8;

    // ---------- Pass 1: denominators ----------
    float lsum[4] = {0.f, 0.f, 0.f, 0.f};
    sv8 kreg[4];
#pragma unroll
    for (int i = 0; i < 4; i++)
        kreg[i] = *(const sv8*)(kg0 + (size_t)(kr + i * 32) * LD + kc);
    for (int s0 = 0; s0 < SS; s0 += SC) {
#pragma unroll
        for (int i = 0; i < 4; i++)
            *(sv8*)&Ks[(kr + i * 32) * KLD + kc] = kreg[i];
        __syncthreads();
        // T14: issue next chunk's K loads now; consumed after the trailing barrier
        if (s0 + SC < SS) {
            const unsigned short* kg = kg0 + (size_t)(s0 + SC) * LD;
#pragma unroll
            for (int i = 0; i < 4; i++)
                kreg[i] = *(const sv8*)(kg + (size_t)(kr + i * 32) * LD + kc);
        }
#pragma unroll
        for (int c = 0; c < 8; c++) {
            sv8 b0 = *(const sv8*)&Ks[(c * 16 + l15) * KLD + quad * 8];
            sv8 b1 = *(const sv8*)&Ks[(c * 16 + l15) * KLD + 32 + quad * 8];
            fv4 sc = {0.f, 0.f, 0.f, 0.f};
            __builtin_amdgcn_s_setprio(1);
            sc = MFMA16(aq0, b0, sc);
            sc = MFMA16(aq1, b1, sc);
            __builtin_amdgcn_s_setprio(0);
#pragma unroll
            for (int r = 0; r < 4; r++) lsum[r] += __expf(sc[r]);
        }
        __syncthreads();
    }
    float inv_l[4];
#pragma unroll
    for (int r = 0; r < 4; r++) {
        float v = lsum[r];
        v += __shfl_xor(v, 1); v += __shfl_xor(v, 2);
        v += __shfl_xor(v, 4); v += __shfl_xor(v, 8);
        inv_l[r] = 1.0f / v;
    }

    // ---------- Pass 2: weights + O ----------
    fv4 oacc[4] = {};
    float* wbase = Wout + ((size_t)((b * HH + h) * LL + l0 + w * 16)) * SS;
    const unsigned short* vg0 = Vtw + (size_t)(b * HH + h) * DD * SS;
    const int vd = t >> 4, vc = (t & 15) * 8;
    sv8 vreg[4];
#pragma unroll
    for (int i = 0; i < 4; i++)
        kreg[i] = *(const sv8*)(kg0 + (size_t)(kr + i * 32) * LD + kc);
#pragma unroll
    for (int i = 0; i < 4; i++)
        vreg[i] = *(const sv8*)(vg0 + (size_t)(vd + i * 16) * SS + vc);
    for (int s0 = 0; s0 < SS; s0 += SC) {
#pragma unroll
        for (int i = 0; i < 4; i++)
            *(sv8*)&Ks[(kr + i * 32) * KLD + kc] = kreg[i];
#pragma unroll
        for (int i = 0; i < 4; i++)
            *(sv8*)&Vs[(vd + i * 16) * VLD + vc] = vreg[i];
        __syncthreads();
        // T14: issue next chunk's K+V loads now
        if (s0 + SC < SS) {
            const unsigned short* kg = kg0 + (size_t)(s0 + SC) * LD;
#pragma unroll
            for (int i = 0; i < 4; i++)
                kreg[i] = *(const sv8*)(kg + (size_t)(kr + i * 32) * LD + kc);
#pragma unroll
            for (int i = 0; i < 4; i++)
                vreg[i] = *(const sv8*)(vg0 + (size_t)(vd + i * 16) * SS + s0 + SC + vc);
        }
        float* wp0 = wbase + s0;
#pragma unroll
        for (int c = 0; c < 8; c++) {
            sv8 b0 = *(const sv8*)&Ks[(c * 16 + l15) * KLD + quad * 8];
            sv8 b1 = *(const sv8*)&Ks[(c * 16 + l15) * KLD + 32 + quad * 8];
            fv4 sc = {0.f, 0.f, 0.f, 0.f};
            __builtin_amdgcn_s_setprio(1);
            sc = MFMA16(aq0, b0, sc);
            sc = MFMA16(aq1, b1, sc);
            __builtin_amdgcn_s_setprio(0);
#pragma unroll
            for (int r = 0; r < 4; r++) {
                float wv = __expf(sc[r]) * inv_l[r];
                wp0[(size_t)(quad * 4 + r) * SS + c * 16 + l15] = wv;
                Ps[(w * 16 + quad * 4 + r) * VLD + c * 16 + l15] = f2bf(wv);
            }
        }
        // P: C-layout -> A-layout via per-wave LDS round trip
        sv8 ap[4];
#pragma unroll
        for (int ks = 0; ks < 4; ks++)
            ap[ks] = *(const sv8*)&Ps[(w * 16 + l15) * VLD + ks * 32 + quad * 8];
        __builtin_amdgcn_s_setprio(1);
#pragma unroll
        for (int dt = 0; dt < 4; dt++)
#pragma unroll
            for (int ks = 0; ks < 4; ks++) {
                sv8 bv = *(const sv8*)&Vs[(dt * 16 + l15) * VLD + ks * 32 + quad * 8];
                oacc[dt] = MFMA16(ap[ks], bv, oacc[dt]);
            }
        __builtin_amdgcn_s_setprio(0);
        __syncthreads();
    }
    unsigned short* obase = Ow + (size_t)(b * LL + l0 + w * 16) * LD + h * DD;
#pragma unroll
    for (int dt = 0; dt < 4; dt++)
#pragma unroll
        for (int r = 0; r < 4; r++)
            obase[(size_t)(quad * 4 + r) * LD + dt * 16 + l15] = f2bf(oacc[dt][r]);
}

// ============================================================================
extern "C" void kernel_launch(void* const* d_in, const int* in_sizes, int n_in,
                              void* d_out, int out_size, void* d_ws, size_t ws_size,
                              hipStream_t stream) {
    const float* latent = (const float*)d_in[0];
    const float* x      = (const float*)d_in[1];
    const float* Wq = (const float*)d_in[2];
    const float* bq = (const float*)d_in[3];
    const float* Wc = (const float*)d_in[4];
    const float* bc = (const float*)d_in[5];
    const float* Wk = (const float*)d_in[6];
    const float* bk = (const float*)d_in[7];
    const float* Wv = (const float*)d_in[8];
    const float* bv = (const float*)d_in[9];
    const float* Wo = (const float*)d_in[10];
    const float* bo = (const float*)d_in[11];

    float* out   = (float*)d_out;              // (2,1024,1024)
    float* attnw = out + (size_t)2 * 1024 * 1024;  // (2,16,1024,4096)

    char* ws = (char*)d_ws;
    size_t off = 0;
    auto alloc = [&](size_t bytes) -> void* {
        void* p = ws + off; off += (bytes + 255) & ~(size_t)255; return p;
    };
    unsigned short* Tc   = (unsigned short*)alloc((size_t)2048 * 256 * 2);
    unsigned short* Tk   = (unsigned short*)alloc((size_t)1024 * 256 * 2);
    unsigned short* Tv   = (unsigned short*)alloc((size_t)1024 * 256 * 2);
    unsigned short* Tq   = (unsigned short*)alloc((size_t)1024 * 1024 * 2);
    unsigned short* To   = (unsigned short*)alloc((size_t)1024 * 1024 * 2);
    unsigned short* comp = (unsigned short*)alloc((size_t)8192 * 256 * 2);
    unsigned short* Kws  = (unsigned short*)alloc((size_t)8192 * 1024 * 2);
    unsigned short* Vws  = (unsigned short*)alloc((size_t)8192 * 1024 * 2);
    unsigned short* Vtws = (unsigned short*)alloc((size_t)8192 * 1024 * 2);
    unsigned short* Qws  = (unsigned short*)alloc((size_t)2048 * 1024 * 2);
    unsigned short* Ows  = (unsigned short*)alloc((size_t)2048 * 1024 * 2);

    transpose_weights<<<768, 256, 0, stream>>>(Wc, Wk, Wv, Wq, Wo, Tc, Tk, Tv, Tq, To);
    // compressed = x @ Wc + bc   (8192 x 256, K=2048)
    gemm_bias<128, 64, true, false><<<dim3(64, 4), 256, 0, stream>>>(
        x, Tc, bc, comp, 8192, 256, 2048, 1.0f);
    // K = comp @ Wk + bk   (8192 x 1024, K=256)
    gemm_bias<128, 128, false, false><<<dim3(64, 8), 256, 0, stream>>>(
        comp, Tk, bk, Kws, 8192, 1024, 256, 1.0f);
    // V = comp @ Wv + bv
    gemm_bias<128, 128, false, false><<<dim3(64, 8), 256, 0, stream>>>(
        comp, Tv, bv, Vws, 8192, 1024, 256, 1.0f);
    // Q = (latent @ Wq + bq) / 8   (2048 x 1024, K=1024)
    gemm_bias<64, 128, true, false><<<dim3(32, 8), 256, 0, stream>>>(
        latent, Tq, bq, Qws, 2048, 1024, 1024, 0.125f);
    // Vt (b,h,d,s)
    transpose_v<<<dim3(64, 16, 2), 256, 0, stream>>>(Vws, Vtws);
    // attention
    attn_kernel<<<512, 256, 0, stream>>>(Qws, Kws, Vtws, attnw, Ows);
    // output = O @ Wo + bo   (2048 x 1024, K=1024) f32
    gemm_bias<64, 128, false, true><<<dim3(32, 8), 256, 0, stream>>>(
        Ows, To, bo, out, 2048, 1024, 1024, 1.0f);
}

// Round 6
// 842.782 us; speedup vs baseline: 1.0574x; 1.0574x over previous
//
#include <hip/hip_runtime.h>

typedef short sv8 __attribute__((ext_vector_type(8)));
typedef float fv4 __attribute__((ext_vector_type(4)));

#define MFMA16(a, b, c) __builtin_amdgcn_mfma_f32_16x16x32_bf16((a), (b), (c), 0, 0, 0)

__device__ __forceinline__ unsigned short f2bf(float f) {
    unsigned u = __builtin_bit_cast(unsigned, f);
    unsigned r = (u + 0x7FFF + ((u >> 16) & 1)) >> 16;
    return (unsigned short)r;
}

// ---------------- dims ----------------
// latent (2,1024,1024)  x (2,4096,2048)
// Wq(1024,1024) bq  Wc(2048,256) bc  Wk(256,1024) bk  Wv(256,1024) bv  Wo(1024,1024) bo
constexpr int BB = 2, LL = 1024, SS = 4096, LD = 1024, HH = 16, DD = 64;

// ============================================================================
// Bulk f32 -> bf16 convert for x and latent (one pass, full BW).
// ============================================================================
constexpr size_t NX = (size_t)2 * 4096 * 2048;   // x elems
constexpr size_t NL = (size_t)2 * 1024 * 1024;   // latent elems

__global__ __launch_bounds__(256) void convert_inputs(
    const float* __restrict__ x, const float* __restrict__ latent,
    unsigned short* __restrict__ xb, unsigned short* __restrict__ lb)
{
    size_t i = ((size_t)blockIdx.x * 256 + threadIdx.x) * 8;
    const float* src; unsigned short* dst;
    if (i < NX) { src = x + i; dst = xb + i; }
    else        { size_t j = i - NX; src = latent + j; dst = lb + j; }
    float4 a = *(const float4*)src;
    float4 b = *(const float4*)(src + 4);
    ushort4 o0 = {f2bf(a.x), f2bf(a.y), f2bf(a.z), f2bf(a.w)};
    ushort4 o1 = {f2bf(b.x), f2bf(b.y), f2bf(b.z), f2bf(b.w)};
    *(ushort4*)dst = o0;
    *(ushort4*)(dst + 4) = o1;
}

// ============================================================================
// Fused weight transpose: W (K x N, f32) -> Wt (N x K, bf16), all 5 weights.
// ============================================================================
__global__ __launch_bounds__(256) void transpose_weights(
    const float* __restrict__ Wc, const float* __restrict__ Wk, const float* __restrict__ Wv,
    const float* __restrict__ Wq, const float* __restrict__ Wo,
    unsigned short* __restrict__ Tc, unsigned short* __restrict__ Tk,
    unsigned short* __restrict__ Tv, unsigned short* __restrict__ Tq,
    unsigned short* __restrict__ To)
{
    __shared__ __align__(16) unsigned short tile[64][68];
    int bid = blockIdx.x;
    const float* W; unsigned short* T; int K, N, tix;
    if (bid < 128)      { W = Wc; T = Tc; K = 2048; N = 256;  tix = bid; }
    else if (bid < 192) { W = Wk; T = Tk; K = 256;  N = 1024; tix = bid - 128; }
    else if (bid < 256) { W = Wv; T = Tv; K = 256;  N = 1024; tix = bid - 192; }
    else if (bid < 512) { W = Wq; T = Tq; K = 1024; N = 1024; tix = bid - 256; }
    else                { W = Wo; T = To; K = 1024; N = 1024; tix = bid - 512; }
    int tn = N >> 6;
    int k0 = (tix / tn) << 6, n0 = (tix % tn) << 6;
    int t = threadIdx.x;
    int r = t >> 4, c4 = (t & 15) * 4;
#pragma unroll
    for (int i = 0; i < 4; i++) {
        int k = r + i * 16;
        float4 f = *(const float4*)(W + (size_t)(k0 + k) * N + n0 + c4);
        tile[k][c4 + 0] = f2bf(f.x); tile[k][c4 + 1] = f2bf(f.y);
        tile[k][c4 + 2] = f2bf(f.z); tile[k][c4 + 3] = f2bf(f.w);
    }
    __syncthreads();
#pragma unroll
    for (int i = 0; i < 4; i++) {
        int n = r + i * 16;
        ushort4 o;
        o.x = tile[c4 + 0][n]; o.y = tile[c4 + 1][n];
        o.z = tile[c4 + 2][n]; o.w = tile[c4 + 3][n];
        *(ushort4*)(T + (size_t)(n0 + n) * K + k0 + c4) = o;
    }
}

// ============================================================================
// V (b, s, h*64+d) bf16 -> Vt (b, h, d, s) bf16
// ============================================================================
__global__ __launch_bounds__(256) void transpose_v(
    const unsigned short* __restrict__ V, unsigned short* __restrict__ Vt)
{
    __shared__ __align__(16) unsigned short tile[64][68];
    int s0 = blockIdx.x * 64;
    int h = blockIdx.y, b = blockIdx.z;
    int t = threadIdx.x;
    int r = t >> 4, c4 = (t & 15) * 4;
#pragma unroll
    for (int i = 0; i < 4; i++) {
        int s = r + i * 16;
        ushort4 v = *(const ushort4*)(V + (size_t)(b * SS + s0 + s) * LD + h * DD + c4);
        tile[s][c4 + 0] = v.x; tile[s][c4 + 1] = v.y;
        tile[s][c4 + 2] = v.z; tile[s][c4 + 3] = v.w;
    }
    __syncthreads();
#pragma unroll
    for (int i = 0; i < 4; i++) {
        int d = r + i * 16;
        ushort4 o;
        o.x = tile[c4 + 0][d]; o.y = tile[c4 + 1][d];
        o.z = tile[c4 + 2][d]; o.w = tile[c4 + 3][d];
        *(ushort4*)(Vt + ((size_t)(b * HH + h) * DD + d) * SS + s0 + c4) = o;
    }
}

// ============================================================================
// Templated GEMM: C(MxN) = (A(MxK) @ B) * scale + bias*scale
// A: bf16 row-major; Bt: N x K bf16 (pre-transposed); C: f32 or bf16.
// 4 waves in 2x2; BK=32; 16x16x32 bf16 MFMA.
// T14 pipeline: prologue-load K-step 0 into regs; each iter ds_writes current
// regs, then issues next K-step's global loads before the MFMA cluster.
// ============================================================================
template<int BM, int BN, bool C_F32>
__global__ __launch_bounds__(256) void gemm_bias(
    const unsigned short* __restrict__ Ag, const unsigned short* __restrict__ Bt,
    const float* __restrict__ bias, void* __restrict__ Cg,
    int M, int N, int K, float scale)
{
    constexpr int LDT = 40;  // 80 B row stride: 16B-aligned, bank-spread
    __shared__ __align__(16) unsigned short As[BM * LDT];
    __shared__ __align__(16) unsigned short Bs[BN * LDT];
    __shared__ float bias_s[BN];
    const int t = threadIdx.x;
    const int m0 = blockIdx.x * BM, n0 = blockIdx.y * BN;
    for (int i = t; i < BN; i += 256) bias_s[i] = bias[n0 + i];
    const int w = t >> 6, lane = t & 63, l15 = lane & 15, quad = lane >> 4;
    constexpr int WM = BM / 2, WN = BN / 2;
    constexpr int MT = WM / 16, NT = WN / 16;
    const int wm = (w >> 1) * WM, wn = (w & 1) * WN;
    fv4 acc[MT][NT] = {};
    // staging: 4 threads per row, sv8 (16B) each -> 32 cols per row
    const int r4 = t >> 2, c8 = (t & 3) * 8;
    constexpr int AI = BM / 64, BI = BN / 64;
    const unsigned short* Aptr = Ag + (size_t)(m0 + r4) * K + c8;
    const unsigned short* Bptr = Bt + (size_t)(n0 + r4) * K + c8;
    sv8 areg[AI], breg[BI];
#pragma unroll
    for (int i = 0; i < AI; i++) areg[i] = *(const sv8*)(Aptr + (size_t)(i * 64) * K);
#pragma unroll
    for (int i = 0; i < BI; i++) breg[i] = *(const sv8*)(Bptr + (size_t)(i * 64) * K);
    for (int k0 = 0; k0 < K; k0 += 32) {
#pragma unroll
        for (int i = 0; i < AI; i++) *(sv8*)&As[(r4 + i * 64) * LDT + c8] = areg[i];
#pragma unroll
        for (int i = 0; i < BI; i++) *(sv8*)&Bs[(r4 + i * 64) * LDT + c8] = breg[i];
        __syncthreads();
        // T14: issue next K-step's global loads; consumed after trailing barrier
        if (k0 + 32 < K) {
#pragma unroll
            for (int i = 0; i < AI; i++)
                areg[i] = *(const sv8*)(Aptr + (size_t)(i * 64) * K + k0 + 32);
#pragma unroll
            for (int i = 0; i < BI; i++)
                breg[i] = *(const sv8*)(Bptr + (size_t)(i * 64) * K + k0 + 32);
        }
        sv8 af[MT], bfr[NT];
#pragma unroll
        for (int mt = 0; mt < MT; mt++)
            af[mt] = *(const sv8*)&As[(wm + mt * 16 + l15) * LDT + quad * 8];
#pragma unroll
        for (int nt = 0; nt < NT; nt++)
            bfr[nt] = *(const sv8*)&Bs[(wn + nt * 16 + l15) * LDT + quad * 8];
#pragma unroll
        for (int mt = 0; mt < MT; mt++)
#pragma unroll
            for (int nt = 0; nt < NT; nt++)
                acc[mt][nt] = MFMA16(af[mt], bfr[nt], acc[mt][nt]);
        __syncthreads();
    }
    // epilogue: C row = quad*4+reg, col = lane&15 (m89-verified layout)
#pragma unroll
    for (int mt = 0; mt < MT; mt++) {
#pragma unroll
        for (int nt = 0; nt < NT; nt++) {
            int col = n0 + wn + nt * 16 + l15;
            float bb = bias_s[wn + nt * 16 + l15];
#pragma unroll
            for (int r = 0; r < 4; r++) {
                int row = m0 + wm + mt * 16 + quad * 4 + r;
                float vv = (acc[mt][nt][r] + bb) * scale;
                if constexpr (C_F32) ((float*)Cg)[(size_t)row * N + col] = vv;
                else ((unsigned short*)Cg)[(size_t)row * N + col] = f2bf(vv);
            }
        }
    }
}

// ============================================================================
// Attention: per WG one (b, h, 64-row L tile). Two passes over S chunks of 128.
// Pass 1: row sums of exp(scores) (no max subtraction; |scores| ~ 1).
// Pass 2: recompute scores, write normalized weights to d_out, PV-accumulate O.
// T14 async-STAGE split + T5 s_setprio around MFMA clusters.
// ============================================================================
constexpr int SC  = 128;
constexpr int KLD = 72;   // 144 B rows (16B mult)
constexpr int VLD = 136;  // 272 B rows (16B mult)

__global__ __launch_bounds__(256) void attn_kernel(
    const unsigned short* __restrict__ Qw,   // (B,L,1024) bf16, pre-scaled 1/8
    const unsigned short* __restrict__ Kw,   // (B,S,1024) bf16
    const unsigned short* __restrict__ Vtw,  // (B,H,D,S) bf16
    float* __restrict__ Wout,                // (B,H,L,S) f32
    unsigned short* __restrict__ Ow)         // (B,L,1024) bf16
{
    __shared__ __align__(16) unsigned short Ks[SC * KLD];
    __shared__ __align__(16) unsigned short Vs[DD * VLD];
    __shared__ __align__(16) unsigned short Ps[4 * 16 * VLD];
    const int bid = blockIdx.x;
    const int lt = bid & 15, h = (bid >> 4) & 15, b = bid >> 8;
    const int l0 = lt * 64;
    const int t = threadIdx.x, w = t >> 6, lane = t & 63, l15 = lane & 15, quad = lane >> 4;

    // Q fragments direct from global (each element used by exactly one lane)
    const unsigned short* qrow = Qw + (size_t)(b * LL + l0 + w * 16 + l15) * LD + h * DD;
    const sv8 aq0 = *(const sv8*)(qrow + quad * 8);
    const sv8 aq1 = *(const sv8*)(qrow + 32 + quad * 8);

    const unsigned short* kg0 = Kw + (size_t)(b * SS) * LD + h * DD;
    const int kr = t >> 3, kc = (t & 7) * 8;

    // ---------- Pass 1: denominators ----------
    float lsum[4] = {0.f, 0.f, 0.f, 0.f};
    sv8 kreg[4];
#pragma unroll
    for (int i = 0; i < 4; i++)
        kreg[i] = *(const sv8*)(kg0 + (size_t)(kr + i * 32) * LD + kc);
    for (int s0 = 0; s0 < SS; s0 += SC) {
#pragma unroll
        for (int i = 0; i < 4; i++)
            *(sv8*)&Ks[(kr + i * 32) * KLD + kc] = kreg[i];
        __syncthreads();
        if (s0 + SC < SS) {
            const unsigned short* kg = kg0 + (size_t)(s0 + SC) * LD;
#pragma unroll
            for (int i = 0; i < 4; i++)
                kreg[i] = *(const sv8*)(kg + (size_t)(kr + i * 32) * LD + kc);
        }
#pragma unroll
        for (int c = 0; c < 8; c++) {
            sv8 b0 = *(const sv8*)&Ks[(c * 16 + l15) * KLD + quad * 8];
            sv8 b1 = *(const sv8*)&Ks[(c * 16 + l15) * KLD + 32 + quad * 8];
            fv4 sc = {0.f, 0.f, 0.f, 0.f};
            __builtin_amdgcn_s_setprio(1);
            sc = MFMA16(aq0, b0, sc);
            sc = MFMA16(aq1, b1, sc);
            __builtin_amdgcn_s_setprio(0);
#pragma unroll
            for (int r = 0; r < 4; r++) lsum[r] += __expf(sc[r]);
        }
        __syncthreads();
    }
    float inv_l[4];
#pragma unroll
    for (int r = 0; r < 4; r++) {
        float v = lsum[r];
        v += __shfl_xor(v, 1); v += __shfl_xor(v, 2);
        v += __shfl_xor(v, 4); v += __shfl_xor(v, 8);
        inv_l[r] = 1.0f / v;
    }

    // ---------- Pass 2: weights + O ----------
    fv4 oacc[4] = {};
    float* wbase = Wout + ((size_t)((b * HH + h) * LL + l0 + w * 16)) * SS;
    const unsigned short* vg0 = Vtw + (size_t)(b * HH + h) * DD * SS;
    const int vd = t >> 4, vc = (t & 15) * 8;
    sv8 vreg[4];
#pragma unroll
    for (int i = 0; i < 4; i++)
        kreg[i] = *(const sv8*)(kg0 + (size_t)(kr + i * 32) * LD + kc);
#pragma unroll
    for (int i = 0; i < 4; i++)
        vreg[i] = *(const sv8*)(vg0 + (size_t)(vd + i * 16) * SS + vc);
    for (int s0 = 0; s0 < SS; s0 += SC) {
#pragma unroll
        for (int i = 0; i < 4; i++)
            *(sv8*)&Ks[(kr + i * 32) * KLD + kc] = kreg[i];
#pragma unroll
        for (int i = 0; i < 4; i++)
            *(sv8*)&Vs[(vd + i * 16) * VLD + vc] = vreg[i];
        __syncthreads();
        if (s0 + SC < SS) {
            const unsigned short* kg = kg0 + (size_t)(s0 + SC) * LD;
#pragma unroll
            for (int i = 0; i < 4; i++)
                kreg[i] = *(const sv8*)(kg + (size_t)(kr + i * 32) * LD + kc);
#pragma unroll
            for (int i = 0; i < 4; i++)
                vreg[i] = *(const sv8*)(vg0 + (size_t)(vd + i * 16) * SS + s0 + SC + vc);
        }
        float* wp0 = wbase + s0;
#pragma unroll
        for (int c = 0; c < 8; c++) {
            sv8 b0 = *(const sv8*)&Ks[(c * 16 + l15) * KLD + quad * 8];
            sv8 b1 = *(const sv8*)&Ks[(c * 16 + l15) * KLD + 32 + quad * 8];
            fv4 sc = {0.f, 0.f, 0.f, 0.f};
            __builtin_amdgcn_s_setprio(1);
            sc = MFMA16(aq0, b0, sc);
            sc = MFMA16(aq1, b1, sc);
            __builtin_amdgcn_s_setprio(0);
#pragma unroll
            for (int r = 0; r < 4; r++) {
                float wv = __expf(sc[r]) * inv_l[r];
                wp0[(size_t)(quad * 4 + r) * SS + c * 16 + l15] = wv;
                Ps[(w * 16 + quad * 4 + r) * VLD + c * 16 + l15] = f2bf(wv);
            }
        }
        // P: C-layout -> A-layout via per-wave LDS round trip
        sv8 ap[4];
#pragma unroll
        for (int ks = 0; ks < 4; ks++)
            ap[ks] = *(const sv8*)&Ps[(w * 16 + l15) * VLD + ks * 32 + quad * 8];
        __builtin_amdgcn_s_setprio(1);
#pragma unroll
        for (int dt = 0; dt < 4; dt++)
#pragma unroll
            for (int ks = 0; ks < 4; ks++) {
                sv8 bv = *(const sv8*)&Vs[(dt * 16 + l15) * VLD + ks * 32 + quad * 8];
                oacc[dt] = MFMA16(ap[ks], bv, oacc[dt]);
            }
        __builtin_amdgcn_s_setprio(0);
        __syncthreads();
    }
    unsigned short* obase = Ow + (size_t)(b * LL + l0 + w * 16) * LD + h * DD;
#pragma unroll
    for (int dt = 0; dt < 4; dt++)
#pragma unroll
        for (int r = 0; r < 4; r++)
            obase[(size_t)(quad * 4 + r) * LD + dt * 16 + l15] = f2bf(oacc[dt][r]);
}

// ============================================================================
extern "C" void kernel_launch(void* const* d_in, const int* in_sizes, int n_in,
                              void* d_out, int out_size, void* d_ws, size_t ws_size,
                              hipStream_t stream) {
    const float* latent = (const float*)d_in[0];
    const float* x      = (const float*)d_in[1];
    const float* Wq = (const float*)d_in[2];
    const float* bq = (const float*)d_in[3];
    const float* Wc = (const float*)d_in[4];
    const float* bc = (const float*)d_in[5];
    const float* Wk = (const float*)d_in[6];
    const float* bk = (const float*)d_in[7];
    const float* Wv = (const float*)d_in[8];
    const float* bv = (const float*)d_in[9];
    const float* Wo = (const float*)d_in[10];
    const float* bo = (const float*)d_in[11];

    float* out   = (float*)d_out;              // (2,1024,1024)
    float* attnw = out + (size_t)2 * 1024 * 1024;  // (2,16,1024,4096)

    char* ws = (char*)d_ws;
    size_t off = 0;
    auto alloc = [&](size_t bytes) -> void* {
        void* p = ws + off; off += (bytes + 255) & ~(size_t)255; return p;
    };
    unsigned short* Tc   = (unsigned short*)alloc((size_t)2048 * 256 * 2);
    unsigned short* Tk   = (unsigned short*)alloc((size_t)1024 * 256 * 2);
    unsigned short* Tv   = (unsigned short*)alloc((size_t)1024 * 256 * 2);
    unsigned short* Tq   = (unsigned short*)alloc((size_t)1024 * 1024 * 2);
    unsigned short* To   = (unsigned short*)alloc((size_t)1024 * 1024 * 2);
    unsigned short* comp = (unsigned short*)alloc((size_t)8192 * 256 * 2);
    unsigned short* Kws  = (unsigned short*)alloc((size_t)8192 * 1024 * 2);
    unsigned short* Vws  = (unsigned short*)alloc((size_t)8192 * 1024 * 2);
    unsigned short* Vtws = (unsigned short*)alloc((size_t)8192 * 1024 * 2);
    unsigned short* Qws  = (unsigned short*)alloc((size_t)2048 * 1024 * 2);
    unsigned short* Ows  = (unsigned short*)alloc((size_t)2048 * 1024 * 2);

    // Aliased scratch (no extra ws): xb spans Kws+Vws (dead until K/V GEMMs),
    // lb aliases Ows (dead until attention). Kws alloc is 16,777,216 B
    // (256-multiple) so Kws and Vws are contiguous -> xb's 33,554,432 B fit.
    unsigned short* xb = Kws;   // (2,4096,2048) bf16
    unsigned short* lb = Ows;   // (2,1024,1024) bf16

    // x, latent -> bf16 (one pass)
    convert_inputs<<<9216, 256, 0, stream>>>(x, latent, xb, lb);
    transpose_weights<<<768, 256, 0, stream>>>(Wc, Wk, Wv, Wq, Wo, Tc, Tk, Tv, Tq, To);
    // compressed = x @ Wc + bc   (8192 x 256, K=2048)
    gemm_bias<128, 64, false><<<dim3(64, 4), 256, 0, stream>>>(
        xb, Tc, bc, comp, 8192, 256, 2048, 1.0f);
    // Q = (latent @ Wq + bq) / 8   (2048 x 1024, K=1024)  [before attn: lb aliases Ows]
    gemm_bias<64, 128, false><<<dim3(32, 8), 256, 0, stream>>>(
        lb, Tq, bq, Qws, 2048, 1024, 1024, 0.125f);
    // K = comp @ Wk + bk   (8192 x 1024, K=256)  [overwrites xb - dead]
    gemm_bias<128, 128, false><<<dim3(64, 8), 256, 0, stream>>>(
        comp, Tk, bk, Kws, 8192, 1024, 256, 1.0f);
    // V = comp @ Wv + bv
    gemm_bias<128, 128, false><<<dim3(64, 8), 256, 0, stream>>>(
        comp, Tv, bv, Vws, 8192, 1024, 256, 1.0f);
    // Vt (b,h,d,s)
    transpose_v<<<dim3(64, 16, 2), 256, 0, stream>>>(Vws, Vtws);
    // attention  [writes Ows - lb dead]
    attn_kernel<<<512, 256, 0, stream>>>(Qws, Kws, Vtws, attnw, Ows);
    // output = O @ Wo + bo   (2048 x 1024, K=1024) f32
    gemm_bias<64, 128, true><<<dim3(32, 8), 256, 0, stream>>>(
        Ows, To, bo, out, 2048, 1024, 1024, 1.0f);
}

// Round 12
// 825.112 us; speedup vs baseline: 1.0800x; 1.0214x over previous
//
#include <hip/hip_runtime.h>

typedef short sv8 __attribute__((ext_vector_type(8)));
typedef float fv4 __attribute__((ext_vector_type(4)));

#define MFMA16(a, b, c) __builtin_amdgcn_mfma_f32_16x16x32_bf16((a), (b), (c), 0, 0, 0)

// async global->LDS, 16B per lane, dest = wave-uniform base + lane*16 (m97/m104).
// AS casts via integer round-trip (always-legal int<->ptr casts; AS3 = low 32
// bits of generic LDS VA, matching LLVM addrspacecast semantics).
__device__ __forceinline__ void gload16(const void* g, void* l) {
    __builtin_amdgcn_global_load_lds(
        (const __attribute__((address_space(1))) unsigned int*)(unsigned long long)g,
        (__attribute__((address_space(3))) unsigned int*)(unsigned)(unsigned long long)l,
        16, 0, 0);
}

__device__ __forceinline__ unsigned short f2bf(float f) {
    unsigned u = __builtin_bit_cast(unsigned, f);
    unsigned r = (u + 0x7FFF + ((u >> 16) & 1)) >> 16;
    return (unsigned short)r;
}

// ---------------- dims ----------------
constexpr int BB = 2, LL = 1024, SS = 4096, LD = 1024, HH = 16, DD = 64;

// ============================================================================
// Bulk f32 -> bf16 convert for x and latent (one pass, full BW).
// ============================================================================
constexpr size_t NX = (size_t)2 * 4096 * 2048;   // x elems
constexpr size_t NL = (size_t)2 * 1024 * 1024;   // latent elems

__global__ __launch_bounds__(256) void convert_inputs(
    const float* __restrict__ x, const float* __restrict__ latent,
    unsigned short* __restrict__ xb, unsigned short* __restrict__ lb)
{
    size_t i = ((size_t)blockIdx.x * 256 + threadIdx.x) * 8;
    const float* src; unsigned short* dst;
    if (i < NX) { src = x + i; dst = xb + i; }
    else        { size_t j = i - NX; src = latent + j; dst = lb + j; }
    float4 a = *(const float4*)src;
    float4 b = *(const float4*)(src + 4);
    ushort4 o0 = {f2bf(a.x), f2bf(a.y), f2bf(a.z), f2bf(a.w)};
    ushort4 o1 = {f2bf(b.x), f2bf(b.y), f2bf(b.z), f2bf(b.w)};
    *(ushort4*)dst = o0;
    *(ushort4*)(dst + 4) = o1;
}

// ============================================================================
// Fused weight transpose: W (K x N, f32) -> Wt (N x K, bf16), all 5 weights.
// ============================================================================
__global__ __launch_bounds__(256) void transpose_weights(
    const float* __restrict__ Wc, const float* __restrict__ Wk, const float* __restrict__ Wv,
    const float* __restrict__ Wq, const float* __restrict__ Wo,
    unsigned short* __restrict__ Tc, unsigned short* __restrict__ Tk,
    unsigned short* __restrict__ Tv, unsigned short* __restrict__ Tq,
    unsigned short* __restrict__ To)
{
    __shared__ __align__(16) unsigned short tile[64][68];
    int bid = blockIdx.x;
    const float* W; unsigned short* T; int K, N, tix;
    if (bid < 128)      { W = Wc; T = Tc; K = 2048; N = 256;  tix = bid; }
    else if (bid < 192) { W = Wk; T = Tk; K = 256;  N = 1024; tix = bid - 128; }
    else if (bid < 256) { W = Wv; T = Tv; K = 256;  N = 1024; tix = bid - 192; }
    else if (bid < 512) { W = Wq; T = Tq; K = 1024; N = 1024; tix = bid - 256; }
    else                { W = Wo; T = To; K = 1024; N = 1024; tix = bid - 512; }
    int tn = N >> 6;
    int k0 = (tix / tn) << 6, n0 = (tix % tn) << 6;
    int t = threadIdx.x;
    int r = t >> 4, c4 = (t & 15) * 4;
#pragma unroll
    for (int i = 0; i < 4; i++) {
        int k = r + i * 16;
        float4 f = *(const float4*)(W + (size_t)(k0 + k) * N + n0 + c4);
        tile[k][c4 + 0] = f2bf(f.x); tile[k][c4 + 1] = f2bf(f.y);
        tile[k][c4 + 2] = f2bf(f.z); tile[k][c4 + 3] = f2bf(f.w);
    }
    __syncthreads();
#pragma unroll
    for (int i = 0; i < 4; i++) {
        int n = r + i * 16;
        ushort4 o;
        o.x = tile[c4 + 0][n]; o.y = tile[c4 + 1][n];
        o.z = tile[c4 + 2][n]; o.w = tile[c4 + 3][n];
        *(ushort4*)(T + (size_t)(n0 + n) * K + k0 + c4) = o;
    }
}

// ============================================================================
// V (b, s, h*64+d) bf16 -> Vt (b, h, d, s) bf16
// ============================================================================
__global__ __launch_bounds__(256) void transpose_v(
    const unsigned short* __restrict__ V, unsigned short* __restrict__ Vt)
{
    __shared__ __align__(16) unsigned short tile[64][68];
    int s0 = blockIdx.x * 64;
    int h = blockIdx.y, b = blockIdx.z;
    int t = threadIdx.x;
    int r = t >> 4, c4 = (t & 15) * 4;
#pragma unroll
    for (int i = 0; i < 4; i++) {
        int s = r + i * 16;
        ushort4 v = *(const ushort4*)(V + (size_t)(b * SS + s0 + s) * LD + h * DD + c4);
        tile[s][c4 + 0] = v.x; tile[s][c4 + 1] = v.y;
        tile[s][c4 + 2] = v.z; tile[s][c4 + 3] = v.w;
    }
    __syncthreads();
#pragma unroll
    for (int i = 0; i < 4; i++) {
        int d = r + i * 16;
        ushort4 o;
        o.x = tile[c4 + 0][d]; o.y = tile[c4 + 1][d];
        o.z = tile[c4 + 2][d]; o.w = tile[c4 + 3][d];
        *(ushort4*)(Vt + ((size_t)(b * HH + h) * DD + d) * SS + s0 + c4) = o;
    }
}

// ============================================================================
// GEMM, m97-class structure: C = (A@B)*scale + bias*scale
// A bf16 row-major (MxK); Bt bf16 (NxK pre-transposed); C f32 or bf16.
// BK=64, double-buffered linear LDS, global_load_lds(16B) staging,
// XOR-swizzle (rule 21: linear dest + inverse-swz source col + swz ds_read),
// one __syncthreads per K-step (prefetch flies under ds_read+MFMA).
// 4 waves in 2x2; wave tile (BM/2)x(BN/2); 16x16x32 MFMA, 2 K-halves.
// LDS row = 64 shorts (128B = 8 units of 16B); swizzle: phys unit = u^(row&7).
// Read spread: 8 lanes on each of 8 units -> all 32 banks active (optimal).
// ============================================================================
template<int BM, int BN, bool C_F32>
__global__ __launch_bounds__(256) void gemm_bias(
    const unsigned short* __restrict__ Ag, const unsigned short* __restrict__ Bt,
    const float* __restrict__ bias, void* __restrict__ Cg,
    int M, int N, int K, float scale)
{
    __shared__ __align__(16) unsigned short As[2][BM * 64];
    __shared__ __align__(16) unsigned short Bs[2][BN * 64];
    __shared__ float bias_s[BN];
    const int t = threadIdx.x;
    const int m0 = blockIdx.x * BM, n0 = blockIdx.y * BN;
    for (int i = t; i < BN; i += 256) bias_s[i] = bias[n0 + i];
    const int w = t >> 6, lane = t & 63, l15 = lane & 15, quad = lane >> 4;
    constexpr int MT = BM / 32, NT = BN / 32;       // frags per wave tile
    const int wm = (w >> 1) * (BM / 2), wn = (w & 1) * (BN / 2);
    fv4 acc[MT][NT] = {};
    // staging geometry: thread t stages row (p*32 + t>>3), phys unit (t&7);
    // source logical unit = (t&7) ^ (row&7); row&7 == (t>>3)&7 for all p.
    const int srow = t >> 3;
    const int usrc = ((t & 7) ^ (srow & 7)) << 3;   // elems
    const unsigned short* ApG = Ag + (size_t)(m0 + srow) * K + usrc;
    const unsigned short* BpG = Bt + (size_t)(n0 + srow) * K + usrc;
    constexpr int PA = BM / 32, PB = BN / 32;
    const int ldsw = w * 512;                       // wave-uniform dest (shorts)
    // fragment read: phys unit = (h*4+quad) ^ (l15&7); (u^4)*8 == u*8 ^ 32
    const int ph0 = (quad ^ (l15 & 7)) << 3;        // shorts, h=0

    int bb = 0;
#pragma unroll
    for (int p = 0; p < PA; p++)
        gload16(ApG + (size_t)(p * 32) * K, &As[0][p * 2048 + ldsw]);
#pragma unroll
    for (int p = 0; p < PB; p++)
        gload16(BpG + (size_t)(p * 32) * K, &Bs[0][p * 2048 + ldsw]);
    for (int k0 = 0; k0 < K; k0 += 64) {
        __syncthreads();   // drains vmcnt: staged tile visible to all waves
        if (k0 + 64 < K) { // prefetch next tile into other buffer
#pragma unroll
            for (int p = 0; p < PA; p++)
                gload16(ApG + (size_t)(p * 32) * K + k0 + 64, &As[bb ^ 1][p * 2048 + ldsw]);
#pragma unroll
            for (int p = 0; p < PB; p++)
                gload16(BpG + (size_t)(p * 32) * K + k0 + 64, &Bs[bb ^ 1][p * 2048 + ldsw]);
        }
        sv8 af[2][MT], bf[2][NT];
#pragma unroll
        for (int h = 0; h < 2; h++) {
#pragma unroll
            for (int mt = 0; mt < MT; mt++)
                af[h][mt] = *(const sv8*)&As[bb][(wm + mt * 16 + l15) * 64 + (ph0 ^ (h << 5))];
#pragma unroll
            for (int nt = 0; nt < NT; nt++)
                bf[h][nt] = *(const sv8*)&Bs[bb][(wn + nt * 16 + l15) * 64 + (ph0 ^ (h << 5))];
        }
#pragma unroll
        for (int h = 0; h < 2; h++)
#pragma unroll
            for (int mt = 0; mt < MT; mt++)
#pragma unroll
                for (int nt = 0; nt < NT; nt++)
                    acc[mt][nt] = MFMA16(af[h][mt], bf[h][nt], acc[mt][nt]);
        bb ^= 1;
    }
    // epilogue: C row = quad*4+reg, col = lane&15 (m89-verified layout)
#pragma unroll
    for (int mt = 0; mt < MT; mt++) {
#pragma unroll
        for (int nt = 0; nt < NT; nt++) {
            int col = n0 + wn + nt * 16 + l15;
            float bb2 = bias_s[wn + nt * 16 + l15];
#pragma unroll
            for (int r = 0; r < 4; r++) {
                int row = m0 + wm + mt * 16 + quad * 4 + r;
                float vv = (acc[mt][nt][r] + bb2) * scale;
                if constexpr (C_F32) ((float*)Cg)[(size_t)row * N + col] = vv;
                else ((unsigned short*)Cg)[(size_t)row * N + col] = f2bf(vv);
            }
        }
    }
}

// ============================================================================
// Attention: per WG one (b, h, 64-row L tile). Two passes over S chunks of 128.
// T14 async-STAGE split + T5 s_setprio around MFMA clusters. (unchanged)
// ============================================================================
constexpr int SC  = 128;
constexpr int KLD = 72;   // 144 B rows (16B mult)
constexpr int VLD = 136;  // 272 B rows (16B mult)

__global__ __launch_bounds__(256) void attn_kernel(
    const unsigned short* __restrict__ Qw,   // (B,L,1024) bf16, pre-scaled 1/8
    const unsigned short* __restrict__ Kw,   // (B,S,1024) bf16
    const unsigned short* __restrict__ Vtw,  // (B,H,D,S) bf16
    float* __restrict__ Wout,                // (B,H,L,S) f32
    unsigned short* __restrict__ Ow)         // (B,L,1024) bf16
{
    __shared__ __align__(16) unsigned short Ks[SC * KLD];
    __shared__ __align__(16) unsigned short Vs[DD * VLD];
    __shared__ __align__(16) unsigned short Ps[4 * 16 * VLD];
    const int bid = blockIdx.x;
    const int lt = bid & 15, h = (bid >> 4) & 15, b = bid >> 8;
    const int l0 = lt * 64;
    const int t = threadIdx.x, w = t >> 6, lane = t & 63, l15 = lane & 15, quad = lane >> 4;

    const unsigned short* qrow = Qw + (size_t)(b * LL + l0 + w * 16 + l15) * LD + h * DD;
    const sv8 aq0 = *(const sv8*)(qrow + quad * 8);
    const sv8 aq1 = *(const sv8*)(qrow + 32 + quad * 8);

    const unsigned short* kg0 = Kw + (size_t)(b * SS) * LD + h * DD;
    const int kr = t >> 3, kc = (t & 7) * 8;

    // ---------- Pass 1: denominators ----------
    float lsum[4] = {0.f, 0.f, 0.f, 0.f};
    sv8 kreg[4];
#pragma unroll
    for (int i = 0; i < 4; i++)
        kreg[i] = *(const sv8*)(kg0 + (size_t)(kr + i * 32) * LD + kc);
    for (int s0 = 0; s0 < SS; s0 += SC) {
#pragma unroll
        for (int i = 0; i < 4; i++)
            *(sv8*)&Ks[(kr + i * 32) * KLD + kc] = kreg[i];
        __syncthreads();
        if (s0 + SC < SS) {
            const unsigned short* kg = kg0 + (size_t)(s0 + SC) * LD;
#pragma unroll
            for (int i = 0; i < 4; i++)
                kreg[i] = *(const sv8*)(kg + (size_t)(kr + i * 32) * LD + kc);
        }
#pragma unroll
        for (int c = 0; c < 8; c++) {
            sv8 b0 = *(const sv8*)&Ks[(c * 16 + l15) * KLD + quad * 8];
            sv8 b1 = *(const sv8*)&Ks[(c * 16 + l15) * KLD + 32 + quad * 8];
            fv4 sc = {0.f, 0.f, 0.f, 0.f};
            __builtin_amdgcn_s_setprio(1);
            sc = MFMA16(aq0, b0, sc);
            sc = MFMA16(aq1, b1, sc);
            __builtin_amdgcn_s_setprio(0);
#pragma unroll
            for (int r = 0; r < 4; r++) lsum[r] += __expf(sc[r]);
        }
        __syncthreads();
    }
    float inv_l[4];
#pragma unroll
    for (int r = 0; r < 4; r++) {
        float v = lsum[r];
        v += __shfl_xor(v, 1); v += __shfl_xor(v, 2);
        v += __shfl_xor(v, 4); v += __shfl_xor(v, 8);
        inv_l[r] = 1.0f / v;
    }

    // ---------- Pass 2: weights + O ----------
    fv4 oacc[4] = {};
    float* wbase = Wout + ((size_t)((b * HH + h) * LL + l0 + w * 16)) * SS;
    const unsigned short* vg0 = Vtw + (size_t)(b * HH + h) * DD * SS;
    const int vd = t >> 4, vc = (t & 15) * 8;
    sv8 vreg[4];
#pragma unroll
    for (int i = 0; i < 4; i++)
        kreg[i] = *(const sv8*)(kg0 + (size_t)(kr + i * 32) * LD + kc);
#pragma unroll
    for (int i = 0; i < 4; i++)
        vreg[i] = *(const sv8*)(vg0 + (size_t)(vd + i * 16) * SS + vc);
    for (int s0 = 0; s0 < SS; s0 += SC) {
#pragma unroll
        for (int i = 0; i < 4; i++)
            *(sv8*)&Ks[(kr + i * 32) * KLD + kc] = kreg[i];
#pragma unroll
        for (int i = 0; i < 4; i++)
            *(sv8*)&Vs[(vd + i * 16) * VLD + vc] = vreg[i];
        __syncthreads();
        if (s0 + SC < SS) {
            const unsigned short* kg = kg0 + (size_t)(s0 + SC) * LD;
#pragma unroll
            for (int i = 0; i < 4; i++)
                kreg[i] = *(const sv8*)(kg + (size_t)(kr + i * 32) * LD + kc);
#pragma unroll
            for (int i = 0; i < 4; i++)
                vreg[i] = *(const sv8*)(vg0 + (size_t)(vd + i * 16) * SS + s0 + SC + vc);
        }
        float* wp0 = wbase + s0;
#pragma unroll
        for (int c = 0; c < 8; c++) {
            sv8 b0 = *(const sv8*)&Ks[(c * 16 + l15) * KLD + quad * 8];
            sv8 b1 = *(const sv8*)&Ks[(c * 16 + l15) * KLD + 32 + quad * 8];
            fv4 sc = {0.f, 0.f, 0.f, 0.f};
            __builtin_amdgcn_s_setprio(1);
            sc = MFMA16(aq0, b0, sc);
            sc = MFMA16(aq1, b1, sc);
            __builtin_amdgcn_s_setprio(0);
#pragma unroll
            for (int r = 0; r < 4; r++) {
                float wv = __expf(sc[r]) * inv_l[r];
                wp0[(size_t)(quad * 4 + r) * SS + c * 16 + l15] = wv;
                Ps[(w * 16 + quad * 4 + r) * VLD + c * 16 + l15] = f2bf(wv);
            }
        }
        sv8 ap[4];
#pragma unroll
        for (int ks = 0; ks < 4; ks++)
            ap[ks] = *(const sv8*)&Ps[(w * 16 + l15) * VLD + ks * 32 + quad * 8];
        __builtin_amdgcn_s_setprio(1);
#pragma unroll
        for (int dt = 0; dt < 4; dt++)
#pragma unroll
            for (int ks = 0; ks < 4; ks++) {
                sv8 bv = *(const sv8*)&Vs[(dt * 16 + l15) * VLD + ks * 32 + quad * 8];
                oacc[dt] = MFMA16(ap[ks], bv, oacc[dt]);
            }
        __builtin_amdgcn_s_setprio(0);
        __syncthreads();
    }
    unsigned short* obase = Ow + (size_t)(b * LL + l0 + w * 16) * LD + h * DD;
#pragma unroll
    for (int dt = 0; dt < 4; dt++)
#pragma unroll
        for (int r = 0; r < 4; r++)
            obase[(size_t)(quad * 4 + r) * LD + dt * 16 + l15] = f2bf(oacc[dt][r]);
}

// ============================================================================
extern "C" void kernel_launch(void* const* d_in, const int* in_sizes, int n_in,
                              void* d_out, int out_size, void* d_ws, size_t ws_size,
                              hipStream_t stream) {
    const float* latent = (const float*)d_in[0];
    const float* x      = (const float*)d_in[1];
    const float* Wq = (const float*)d_in[2];
    const float* bq = (const float*)d_in[3];
    const float* Wc = (const float*)d_in[4];
    const float* bc = (const float*)d_in[5];
    const float* Wk = (const float*)d_in[6];
    const float* bk = (const float*)d_in[7];
    const float* Wv = (const float*)d_in[8];
    const float* bv = (const float*)d_in[9];
    const float* Wo = (const float*)d_in[10];
    const float* bo = (const float*)d_in[11];

    float* out   = (float*)d_out;              // (2,1024,1024)
    float* attnw = out + (size_t)2 * 1024 * 1024;  // (2,16,1024,4096)

    char* ws = (char*)d_ws;
    size_t off = 0;
    auto alloc = [&](size_t bytes) -> void* {
        void* p = ws + off; off += (bytes + 255) & ~(size_t)255; return p;
    };
    unsigned short* Tc   = (unsigned short*)alloc((size_t)2048 * 256 * 2);
    unsigned short* Tk   = (unsigned short*)alloc((size_t)1024 * 256 * 2);
    unsigned short* Tv   = (unsigned short*)alloc((size_t)1024 * 256 * 2);
    unsigned short* Tq   = (unsigned short*)alloc((size_t)1024 * 1024 * 2);
    unsigned short* To   = (unsigned short*)alloc((size_t)1024 * 1024 * 2);
    unsigned short* comp = (unsigned short*)alloc((size_t)8192 * 256 * 2);
    unsigned short* Kws  = (unsigned short*)alloc((size_t)8192 * 1024 * 2);
    unsigned short* Vws  = (unsigned short*)alloc((size_t)8192 * 1024 * 2);
    unsigned short* Vtws = (unsigned short*)alloc((size_t)8192 * 1024 * 2);
    unsigned short* Qws  = (unsigned short*)alloc((size_t)2048 * 1024 * 2);
    unsigned short* Ows  = (unsigned short*)alloc((size_t)2048 * 1024 * 2);

    // Aliased scratch: xb spans Kws+Vws (dead until K/V GEMMs), lb aliases Ows
    // (dead until attention). Launch order respects lifetimes.
    unsigned short* xb = Kws;   // (2,4096,2048) bf16
    unsigned short* lb = Ows;   // (2,1024,1024) bf16

    convert_inputs<<<9216, 256, 0, stream>>>(x, latent, xb, lb);
    transpose_weights<<<768, 256, 0, stream>>>(Wc, Wk, Wv, Wq, Wo, Tc, Tk, Tv, Tq, To);
    // compressed = x @ Wc + bc   (8192 x 256, K=2048)
    gemm_bias<128, 64, false><<<dim3(64, 4), 256, 0, stream>>>(
        xb, Tc, bc, comp, 8192, 256, 2048, 1.0f);
    // Q = (latent @ Wq + bq) / 8   (2048 x 1024, K=1024)  [before attn: lb aliases Ows]
    gemm_bias<64, 128, false><<<dim3(32, 8), 256, 0, stream>>>(
        lb, Tq, bq, Qws, 2048, 1024, 1024, 0.125f);
    // K = comp @ Wk + bk   (8192 x 1024, K=256)  [overwrites xb - dead]
    gemm_bias<128, 128, false><<<dim3(64, 8), 256, 0, stream>>>(
        comp, Tk, bk, Kws, 8192, 1024, 256, 1.0f);
    // V = comp @ Wv + bv
    gemm_bias<128, 128, false><<<dim3(64, 8), 256, 0, stream>>>(
        comp, Tv, bv, Vws, 8192, 1024, 256, 1.0f);
    // Vt (b,h,d,s)
    transpose_v<<<dim3(64, 16, 2), 256, 0, stream>>>(Vws, Vtws);
    // attention  [writes Ows - lb dead]
    attn_kernel<<<512, 256, 0, stream>>>(Qws, Kws, Vtws, attnw, Ows);
    // output = O @ Wo + bo   (2048 x 1024, K=1024) f32
    gemm_bias<64, 128, true><<<dim3(32, 8), 256, 0, stream>>>(
        Ows, To, bo, out, 2048, 1024, 1024, 1.0f);
}